// Round 1
// baseline (754.097 us; speedup 1.0000x reference)
//
#include <hip/hip_runtime.h>

// C51 distributional Q target: fused MLP(160->512->256->128->251, LN+SiLU) +
// softmax + categorical projection. bf16 MFMA (16x16x32) for all GEMMs,
// fp32 for LN/softmax/projection. One block = 64 rows, 256 threads (4 waves
// split N). Weights pre-transposed to bf16 [N][K] in d_ws by prep kernel.

#define THREADS 256

typedef __attribute__((ext_vector_type(8))) short short8v;
typedef __attribute__((ext_vector_type(4))) float f32x4;

__device__ __forceinline__ unsigned short f2bf(float f) {
  union { float f; unsigned u; } v; v.f = f;
  unsigned u = v.u;
  u += 0x7fffu + ((u >> 16) & 1u);   // RNE
  return (unsigned short)(u >> 16);
}
__device__ __forceinline__ float bf2f(unsigned short h) {
  union { unsigned u; float f; } v; v.u = ((unsigned)h) << 16;
  return v.f;
}

// ---------------- prep: weights fp32 [K][N] -> bf16 [N][K] in ws -------------
// W1T @0 (512x160), W2T @81920 (256x512), W3T @212992 (128x256),
// W4T @245760 (256x128, rows n>=251 zero-padded)
__global__ void prep_kernel(const float* __restrict__ W1, const float* __restrict__ W2,
                            const float* __restrict__ W3, const float* __restrict__ W4,
                            unsigned short* __restrict__ ws) {
  int i = blockIdx.x * THREADS + threadIdx.x;
  if (i < 81920) {
    int n = i / 160, k = i - n * 160;
    ws[i] = f2bf(W1[k * 512 + n]);
  } else if (i < 212992) {
    int j = i - 81920; int n = j >> 9, k = j & 511;
    ws[i] = f2bf(W2[k * 256 + n]);
  } else if (i < 245760) {
    int j = i - 212992; int n = j >> 8, k = j & 255;
    ws[i] = f2bf(W3[k * 128 + n]);
  } else if (i < 278528) {
    int j = i - 245760; int n = j >> 7, k = j & 127;
    ws[i] = (n < 251) ? f2bf(W4[k * 251 + n]) : (unsigned short)0;
  }
}

// LDS layout (bytes). Aliased regions:
//  A: H1 bf16 [64][512] (swz)  |  proj f32 [64][251]
//  B: X  bf16 [64][160] (swz)  |  H2 bf16 [64][256] (swz)
//  C: H3 bf16 [64][128] (swz)
#define OFF_A   0
#define OFF_B   65536
#define OFF_C   98304
#define OFF_ZS  114688
#define OFF_RW  115712
#define OFF_BT  115968
#define OFF_DC  116224
#define OFF_B1  116480
#define OFF_G1  118528
#define OFF_E1  120576
#define OFF_B2  122624
#define OFF_G2  123648
#define OFF_E2  124672
#define OFF_B3  125696
#define OFF_G3  126208
#define OFF_E3  126720
#define OFF_B4  127232
#define OFF_RED 128256
#define LDS_TOTAL 129280

// A from swizzled LDS [64][KD] bf16, B from global WT [N][KD] bf16.
// MFMA 16x16x32 bf16: A lane: m=lane&15, k=(lane>>4)*8+i ; B lane: n=lane&15,
// k=(lane>>4)*8+i ; C: col=lane&15, row=(lane>>4)*4+reg.
template<int KD, int NCH>
__device__ __forceinline__ void gemm_tiles(const unsigned char* __restrict__ Ab,
                                           const unsigned short* __restrict__ WT,
                                           int n0, f32x4 (&acc)[NCH][4]) {
  const int lane = threadIdx.x & 63;
  const int lm = lane & 15;
  const int kg = lane >> 4;
#pragma unroll 2
  for (int ks = 0; ks < KD / 32; ++ks) {
    const int kk = ks * 32 + kg * 8;
    short8v a[4];
#pragma unroll
    for (int mt = 0; mt < 4; ++mt) {
      const int r = mt * 16 + lm;
      int byte = r * (KD * 2) + kk * 2;
      byte ^= ((r & 7) << 4);
      a[mt] = *(const short8v*)(Ab + byte);
    }
#pragma unroll
    for (int nt = 0; nt < NCH; ++nt) {
      const short8v b = *(const short8v*)(WT + (size_t)(n0 + nt * 16 + lm) * KD + kk);
#pragma unroll
      for (int mt = 0; mt < 4; ++mt)
        acc[nt][mt] = __builtin_amdgcn_mfma_f32_16x16x32_bf16(a[mt], b, acc[nt][mt], 0, 0, 0);
    }
  }
}

// +bias, store bf16 raw (pre-LN) into swizzled LDS [64][ND]
template<int ND, int NCH>
__device__ __forceinline__ void store_h(unsigned char* __restrict__ Hb,
                                        const float* __restrict__ biasL,
                                        int n0, f32x4 (&acc)[NCH][4]) {
  const int lane = threadIdx.x & 63;
  const int lm = lane & 15;
  const int kg = lane >> 4;
#pragma unroll
  for (int nt = 0; nt < NCH; ++nt) {
    const int n = n0 + nt * 16 + lm;
    const float bn = biasL[n];
#pragma unroll
    for (int mt = 0; mt < 4; ++mt) {
#pragma unroll
      for (int rg = 0; rg < 4; ++rg) {
        const int r = mt * 16 + kg * 4 + rg;
        int byte = r * (ND * 2) + n * 2;
        byte ^= ((r & 7) << 4);
        *(unsigned short*)(Hb + byte) = f2bf(acc[nt][mt][rg] + bn);
      }
    }
  }
}

// in-place LayerNorm + SiLU on bf16 [64][ND] (swizzled). 4 threads per row.
template<int ND>
__device__ __forceinline__ void ln_silu(unsigned char* __restrict__ Hb,
                                        const float* __restrict__ gL,
                                        const float* __restrict__ beL) {
  const int tid = threadIdx.x;
  const int r = tid >> 2;
  const int s = tid & 3;
  constexpr int PC = ND / 32;  // 8-elem chunks per thread
  short8v vv[PC];
  float sum = 0.f, sq = 0.f;
#pragma unroll
  for (int c = 0; c < PC; ++c) {
    const int col = (s * PC + c) * 8;
    int byte = r * (ND * 2) + col * 2;
    byte ^= ((r & 7) << 4);
    vv[c] = *(const short8v*)(Hb + byte);
#pragma unroll
    for (int j = 0; j < 8; ++j) {
      float x = bf2f((unsigned short)vv[c][j]);
      sum += x; sq += x * x;
    }
  }
  sum += __shfl_xor(sum, 1); sum += __shfl_xor(sum, 2);
  sq  += __shfl_xor(sq, 1);  sq  += __shfl_xor(sq, 2);
  const float mean = sum * (1.0f / ND);
  const float var  = sq * (1.0f / ND) - mean * mean;
  const float rstd = rsqrtf(var + 1e-5f);
#pragma unroll
  for (int c = 0; c < PC; ++c) {
    const int col = (s * PC + c) * 8;
    int byte = r * (ND * 2) + col * 2;
    byte ^= ((r & 7) << 4);
    short8v o;
#pragma unroll
    for (int j = 0; j < 8; ++j) {
      float x = bf2f((unsigned short)vv[c][j]);
      float y = (x - mean) * rstd * gL[col + j] + beL[col + j];
      float sg = 1.0f / (1.0f + __expf(-y));
      o[j] = (short)f2bf(y * sg);
    }
    *(short8v*)(Hb + byte) = o;
  }
}

__global__ __launch_bounds__(THREADS, 1) void fused_kernel(
    const float* __restrict__ obs, const float* __restrict__ actions,
    const float* __restrict__ rewards, const float* __restrict__ bootstrap,
    const float* __restrict__ discount, const float* __restrict__ q_support,
    const float* __restrict__ b1, const float* __restrict__ g1, const float* __restrict__ be1,
    const float* __restrict__ b2, const float* __restrict__ g2, const float* __restrict__ be2,
    const float* __restrict__ b3, const float* __restrict__ g3, const float* __restrict__ be3,
    const float* __restrict__ b4,
    const unsigned short* __restrict__ ws,
    float* __restrict__ out)
{
  __shared__ __align__(16) unsigned char smem[LDS_TOTAL];
  const int tid  = threadIdx.x;
  const int wid  = tid >> 6;
  const int lane = tid & 63;
  const int lm   = lane & 15;
  const int kg   = lane >> 4;
  const int row0 = blockIdx.x * 64;

  const unsigned short* W1T = ws;
  const unsigned short* W2T = ws + 81920;
  const unsigned short* W3T = ws + 212992;
  const unsigned short* W4T = ws + 245760;

  float* zsL  = (float*)(smem + OFF_ZS);
  float* rewL = (float*)(smem + OFF_RW);
  float* btL  = (float*)(smem + OFF_BT);
  float* dcL  = (float*)(smem + OFF_DC);
  float* b1L  = (float*)(smem + OFF_B1);
  float* g1L  = (float*)(smem + OFF_G1);
  float* e1L  = (float*)(smem + OFF_E1);
  float* b2L  = (float*)(smem + OFF_B2);
  float* g2L  = (float*)(smem + OFF_G2);
  float* e2L  = (float*)(smem + OFF_E2);
  float* b3L  = (float*)(smem + OFF_B3);
  float* g3L  = (float*)(smem + OFF_G3);
  float* e3L  = (float*)(smem + OFF_E3);
  float* b4L  = (float*)(smem + OFF_B4);
  float* redL = (float*)(smem + OFF_RED);

  // ---- stage params + per-row scalars ----
  for (int i = tid; i < 512; i += THREADS) { b1L[i] = b1[i]; g1L[i] = g1[i]; e1L[i] = be1[i]; }
  {
    const int i = tid;  // exactly 256
    b2L[i] = b2[i]; g2L[i] = g2[i]; e2L[i] = be2[i];
    zsL[i] = (i < 251) ? q_support[i] : 0.f;
    b4L[i] = (i < 251) ? b4[i] : 0.f;
    if (i < 128) { b3L[i] = b3[i]; g3L[i] = g3[i]; e3L[i] = be3[i]; }
    if (i < 64) {
      rewL[i] = rewards[row0 + i];
      btL[i]  = bootstrap[row0 + i];
      dcL[i]  = discount[row0 + i];
    }
  }

  // ---- stage X = concat(obs, actions) as bf16 [64][160], swizzled ----
  {
    unsigned char* Xb = smem + OFF_B;
#pragma unroll
    for (int it = 0; it < 10; ++it) {
      const int q  = it * THREADS + tid;      // 0..2559, 40 float4 per row
      const int r  = q / 40;
      const int c4 = (q - r * 40) * 4;
      float4 v;
      if (c4 < 128) v = *(const float4*)(obs + (size_t)(row0 + r) * 128 + c4);
      else          v = *(const float4*)(actions + (size_t)(row0 + r) * 32 + (c4 - 128));
      ushort4 h;
      h.x = f2bf(v.x); h.y = f2bf(v.y); h.z = f2bf(v.z); h.w = f2bf(v.w);
      int byte = r * 320 + c4 * 2;
      byte ^= ((r & 7) << 4);
      *(ushort4*)(Xb + byte) = h;
    }
  }
  __syncthreads();

  // ---- GEMM1: [64,160]x[160,512] -> H1, two 64-col chunks per wave ----
  for (int ch = 0; ch < 2; ++ch) {
    f32x4 acc[4][4];
#pragma unroll
    for (int i = 0; i < 4; ++i)
#pragma unroll
      for (int j = 0; j < 4; ++j) acc[i][j] = f32x4{0.f, 0.f, 0.f, 0.f};
    const int n0 = wid * 128 + ch * 64;
    gemm_tiles<160, 4>(smem + OFF_B, W1T, n0, acc);
    store_h<512, 4>(smem + OFF_A, b1L, n0, acc);
  }
  __syncthreads();
  ln_silu<512>(smem + OFF_A, g1L, e1L);
  __syncthreads();

  // ---- GEMM2: [64,512]x[512,256] -> H2 ----
  {
    f32x4 acc[4][4];
#pragma unroll
    for (int i = 0; i < 4; ++i)
#pragma unroll
      for (int j = 0; j < 4; ++j) acc[i][j] = f32x4{0.f, 0.f, 0.f, 0.f};
    gemm_tiles<512, 4>(smem + OFF_A, W2T, wid * 64, acc);
    store_h<256, 4>(smem + OFF_B, b2L, wid * 64, acc);
  }
  __syncthreads();
  ln_silu<256>(smem + OFF_B, g2L, e2L);
  __syncthreads();

  // ---- GEMM3: [64,256]x[256,128] -> H3 ----
  {
    f32x4 acc[2][4];
#pragma unroll
    for (int i = 0; i < 2; ++i)
#pragma unroll
      for (int j = 0; j < 4; ++j) acc[i][j] = f32x4{0.f, 0.f, 0.f, 0.f};
    gemm_tiles<256, 2>(smem + OFF_B, W3T, wid * 32, acc);
    store_h<128, 2>(smem + OFF_C, b3L, wid * 32, acc);
  }
  __syncthreads();
  ln_silu<128>(smem + OFF_C, g3L, e3L);
  __syncthreads();

  // ---- zero projection buffer (aliases H1, dead since GEMM2) ----
  float* projL = (float*)(smem + OFF_A);
  for (int i = tid; i < 64 * 251; i += THREADS) projL[i] = 0.f;

  // ---- GEMM4: [64,128]x[128,256pad] logits in registers ----
  f32x4 acc4[4][4];
#pragma unroll
  for (int i = 0; i < 4; ++i)
#pragma unroll
    for (int j = 0; j < 4; ++j) acc4[i][j] = f32x4{0.f, 0.f, 0.f, 0.f};
  gemm_tiles<128, 4>(smem + OFF_C, W4T, wid * 64, acc4);

  float lv[4][4][4];
#pragma unroll
  for (int nt = 0; nt < 4; ++nt) {
    const int n = wid * 64 + nt * 16 + lm;
    const float bb = b4L[n];
    const bool ok = (n < 251);
#pragma unroll
    for (int mt = 0; mt < 4; ++mt)
#pragma unroll
      for (int rg = 0; rg < 4; ++rg)
        lv[nt][mt][rg] = ok ? (acc4[nt][mt][rg] + bb) : -1e30f;
  }

  // ---- softmax over 251 cols per row ----
  float rmx[4][4];
#pragma unroll
  for (int mt = 0; mt < 4; ++mt)
#pragma unroll
    for (int rg = 0; rg < 4; ++rg) {
      float m = fmaxf(fmaxf(lv[0][mt][rg], lv[1][mt][rg]),
                      fmaxf(lv[2][mt][rg], lv[3][mt][rg]));
      m = fmaxf(m, __shfl_xor(m, 1));
      m = fmaxf(m, __shfl_xor(m, 2));
      m = fmaxf(m, __shfl_xor(m, 4));
      m = fmaxf(m, __shfl_xor(m, 8));
      rmx[mt][rg] = m;
    }
  if (lm == 0) {
#pragma unroll
    for (int mt = 0; mt < 4; ++mt)
#pragma unroll
      for (int rg = 0; rg < 4; ++rg)
        redL[(mt * 16 + kg * 4 + rg) * 4 + wid] = rmx[mt][rg];
  }
  __syncthreads();
  float gmx[4][4];
#pragma unroll
  for (int mt = 0; mt < 4; ++mt)
#pragma unroll
    for (int rg = 0; rg < 4; ++rg) {
      const float* p = redL + (mt * 16 + kg * 4 + rg) * 4;
      gmx[mt][rg] = fmaxf(fmaxf(p[0], p[1]), fmaxf(p[2], p[3]));
    }
  __syncthreads();

  float sm[4][4];
#pragma unroll
  for (int mt = 0; mt < 4; ++mt)
#pragma unroll
    for (int rg = 0; rg < 4; ++rg) sm[mt][rg] = 0.f;
#pragma unroll
  for (int nt = 0; nt < 4; ++nt)
#pragma unroll
    for (int mt = 0; mt < 4; ++mt)
#pragma unroll
      for (int rg = 0; rg < 4; ++rg) {
        float e = __expf(lv[nt][mt][rg] - gmx[mt][rg]);
        lv[nt][mt][rg] = e;
        sm[mt][rg] += e;
      }
#pragma unroll
  for (int mt = 0; mt < 4; ++mt)
#pragma unroll
    for (int rg = 0; rg < 4; ++rg) {
      float s = sm[mt][rg];
      s += __shfl_xor(s, 1); s += __shfl_xor(s, 2);
      s += __shfl_xor(s, 4); s += __shfl_xor(s, 8);
      sm[mt][rg] = s;
    }
  if (lm == 0) {
#pragma unroll
    for (int mt = 0; mt < 4; ++mt)
#pragma unroll
      for (int rg = 0; rg < 4; ++rg)
        redL[(mt * 16 + kg * 4 + rg) * 4 + wid] = sm[mt][rg];
  }
  __syncthreads();
  float inv[4][4];
#pragma unroll
  for (int mt = 0; mt < 4; ++mt)
#pragma unroll
    for (int rg = 0; rg < 4; ++rg) {
      const float* p = redL + (mt * 16 + kg * 4 + rg) * 4;
      inv[mt][rg] = 1.0f / (p[0] + p[1] + p[2] + p[3]);
    }

  // ---- C51 projection scatter (bit-exact bin math vs numpy) ----
  constexpr float DZF = 20.0f / 250.0f;
#pragma unroll
  for (int nt = 0; nt < 4; ++nt) {
    const int n = wid * 64 + nt * 16 + lm;
    if (n < 251) {
      const float z = zsL[n];
#pragma unroll
      for (int mt = 0; mt < 4; ++mt) {
#pragma unroll
        for (int rg = 0; rg < 4; ++rg) {
          const int r = mt * 16 + kg * 4 + rg;
          const float p = lv[nt][mt][rg] * inv[mt][rg];
          float t = __fadd_rn(rewL[r], __fmul_rn(__fmul_rn(btL[r], dcL[r]), z));
          t = fminf(fmaxf(t, -10.0f), 10.0f);
          const float bfr = __fdiv_rn(__fsub_rn(t, -10.0f), DZF);
          const float fl = floorf(bfr), fu = ceilf(bfr);
          int l = (int)fl, u = (int)fu;
          if (fl == fu) { if (l > 0) --l; else ++u; }
          atomicAdd(projL + r * 251 + l, p * ((float)u - bfr));
          atomicAdd(projL + r * 251 + u, p * (bfr - (float)l));
        }
      }
    }
  }
  __syncthreads();

  // ---- write out ----
  for (int i = tid; i < 64 * 251; i += THREADS) {
    const int r = i / 251;
    const int c = i - r * 251;
    out[(size_t)(row0 + r) * 251 + c] = projL[i];
  }
}

extern "C" void kernel_launch(void* const* d_in, const int* in_sizes, int n_in,
                              void* d_out, int out_size, void* d_ws, size_t ws_size,
                              hipStream_t stream) {
  const float* obs  = (const float*)d_in[0];
  const float* act  = (const float*)d_in[1];
  const float* rew  = (const float*)d_in[2];
  const float* boot = (const float*)d_in[3];
  const float* disc = (const float*)d_in[4];
  const float* zs   = (const float*)d_in[5];
  const float* W1   = (const float*)d_in[6];
  const float* b1   = (const float*)d_in[7];
  const float* g1   = (const float*)d_in[8];
  const float* be1  = (const float*)d_in[9];
  const float* W2   = (const float*)d_in[10];
  const float* b2   = (const float*)d_in[11];
  const float* g2   = (const float*)d_in[12];
  const float* be2  = (const float*)d_in[13];
  const float* W3   = (const float*)d_in[14];
  const float* b3   = (const float*)d_in[15];
  const float* g3   = (const float*)d_in[16];
  const float* be3  = (const float*)d_in[17];
  const float* W4   = (const float*)d_in[18];
  const float* b4   = (const float*)d_in[19];
  unsigned short* ws = (unsigned short*)d_ws;

  const int Bn = in_sizes[2];          // batch = 131072
  prep_kernel<<<(278528 + THREADS - 1) / THREADS, THREADS, 0, stream>>>(W1, W2, W3, W4, ws);
  fused_kernel<<<Bn / 64, THREADS, 0, stream>>>(obs, act, rew, boot, disc, zs,
      b1, g1, be1, b2, g2, be2, b3, g3, be3, b4, ws, (float*)d_out);
}

// Round 2
// 533.897 us; speedup vs baseline: 1.4124x; 1.4124x over previous
//
#include <hip/hip_runtime.h>

// C51 distributional Q target, restructured: operand-swapped MFMA
// (D = W * X^T) so each lane owns 4 consecutive FEATURES of one batch ROW.
// LN/SiLU/softmax fully in registers; activations stored once (packed b64).
// 32 rows/block, 256 threads = 4 waves; wave = feature-quarter x 2 row-tiles.
// LDS 61KB -> 2 blocks/CU (8 waves/CU).

#define THREADS 256

typedef __attribute__((ext_vector_type(8))) short short8v;
typedef __attribute__((ext_vector_type(4))) float f32x4;

__device__ __forceinline__ unsigned short f2bf(float f) {
  union { float f; unsigned u; } v; v.f = f;
  unsigned u = v.u;
  u += 0x7fffu + ((u >> 16) & 1u);   // RNE
  return (unsigned short)(u >> 16);
}
__device__ __forceinline__ unsigned pack2bf(float a, float b) {
  return (unsigned)f2bf(a) | ((unsigned)f2bf(b) << 16);
}

// ---------------- prep: weights fp32 [K][N] -> bf16 [N][K] in ws -------------
// W1T @0 (512x160), W2T @81920 (256x512), W3T @212992 (128x256),
// W4T @245760 (256x128, rows n>=251 zero-padded)
__global__ void prep_kernel(const float* __restrict__ W1, const float* __restrict__ W2,
                            const float* __restrict__ W3, const float* __restrict__ W4,
                            unsigned short* __restrict__ ws) {
  int i = blockIdx.x * THREADS + threadIdx.x;
  if (i < 81920) {
    int n = i / 160, k = i - n * 160;
    ws[i] = f2bf(W1[k * 512 + n]);
  } else if (i < 212992) {
    int j = i - 81920; int n = j >> 9, k = j & 511;
    ws[i] = f2bf(W2[k * 256 + n]);
  } else if (i < 245760) {
    int j = i - 212992; int n = j >> 8, k = j & 255;
    ws[i] = f2bf(W3[k * 128 + n]);
  } else if (i < 278528) {
    int j = i - 245760; int n = j >> 7, k = j & 127;
    ws[i] = (n < 251) ? f2bf(W4[k * 251 + n]) : (unsigned short)0;
  }
}

// LDS layout (bytes), aliased:
//  H1 bf16 [32][512] swz (32K)  |  proj f32 [32][251] (31.4K)
//  H2 bf16 [32][256] swz (16K)
//  X  bf16 [32][160] swz (10K)  |  H3 bf16 [32][128] swz (8K)
#define OFF_H1  0
#define OFF_H2  32768
#define OFF_X   49152
#define OFF_ZS  59392
#define OFF_B4  60416
#define OFF_RED 61440
#define LDS_TOTAL 62464

// GEMM: acc[ft][rt] += WT[fbase+ft*16+..][k] * H[rt*16+..][k]
// MFMA 16x16x32 bf16, A = weight rows (m=feature), B = act rows (n=batch row).
// D: lane&15 = batch row in tile, (lane>>4)*4+reg = feature in tile.
template<int KD, int NFT>
__device__ __forceinline__ void gemm_w(const unsigned short* __restrict__ WT,
                                       const unsigned char* __restrict__ Hb,
                                       int fbase, f32x4 (&acc)[NFT][2]) {
  const int lane = threadIdx.x & 63;
  const int lm = lane & 15, kg = lane >> 4;
#pragma unroll 4
  for (int ks = 0; ks < KD / 32; ++ks) {
    const int kk = ks * 32 + kg * 8;
    short8v b[2];
#pragma unroll
    for (int rt = 0; rt < 2; ++rt) {
      const int r = rt * 16 + lm;
      int byte = r * (KD * 2) + kk * 2;
      byte ^= ((r & 7) << 4);
      b[rt] = *(const short8v*)(Hb + byte);
    }
#pragma unroll
    for (int ft = 0; ft < NFT; ++ft) {
      const short8v a = *(const short8v*)(WT + (size_t)(fbase + ft * 16 + lm) * KD + kk);
      acc[ft][0] = __builtin_amdgcn_mfma_f32_16x16x32_bf16(a, b[0], acc[ft][0], 0, 0, 0);
      acc[ft][1] = __builtin_amdgcn_mfma_f32_16x16x32_bf16(a, b[1], acc[ft][1], 0, 0, 0);
    }
  }
}

// bias + LayerNorm + SiLU entirely in registers, then one packed b64 store
// per (ft, rt) into swizzled LDS [32][ND] bf16.
template<int ND, int NFT>
__device__ __forceinline__ void ln_silu_store(
    f32x4 (&acc)[NFT][2],
    const float* __restrict__ bias, const float* __restrict__ g,
    const float* __restrict__ be, unsigned char* __restrict__ Hb,
    float* __restrict__ redL, int fq)
{
  const int lane = threadIdx.x & 63;
  const int lm = lane & 15, kg = lane >> 4;
  const int fq0 = fq * (ND / 4);
  float s[2] = {0.f, 0.f}, q[2] = {0.f, 0.f};
#pragma unroll
  for (int ft = 0; ft < NFT; ++ft) {
    const int f0 = fq0 + ft * 16 + kg * 4;
    const f32x4 bb = *(const f32x4*)(bias + f0);
#pragma unroll
    for (int rt = 0; rt < 2; ++rt)
#pragma unroll
      for (int rg = 0; rg < 4; ++rg) {
        float x = acc[ft][rt][rg] + bb[rg];
        acc[ft][rt][rg] = x;
        s[rt] += x; q[rt] += x * x;
      }
  }
#pragma unroll
  for (int rt = 0; rt < 2; ++rt) {
    s[rt] += __shfl_xor(s[rt], 16); s[rt] += __shfl_xor(s[rt], 32);
    q[rt] += __shfl_xor(q[rt], 16); q[rt] += __shfl_xor(q[rt], 32);
  }
  if (lane < 16) {
#pragma unroll
    for (int rt = 0; rt < 2; ++rt) {
      redL[((rt * 16 + lm) * 4 + fq) * 2    ] = s[rt];
      redL[((rt * 16 + lm) * 4 + fq) * 2 + 1] = q[rt];
    }
  }
  __syncthreads();
  float mean[2], rstd[2];
#pragma unroll
  for (int rt = 0; rt < 2; ++rt) {
    const int row = rt * 16 + lm;
    float S = redL[row * 8 + 0] + redL[row * 8 + 2] + redL[row * 8 + 4] + redL[row * 8 + 6];
    float Q = redL[row * 8 + 1] + redL[row * 8 + 3] + redL[row * 8 + 5] + redL[row * 8 + 7];
    float m = S * (1.0f / ND);
    float v = Q * (1.0f / ND) - m * m;
    mean[rt] = m; rstd[rt] = rsqrtf(v + 1e-5f);
  }
#pragma unroll
  for (int ft = 0; ft < NFT; ++ft) {
    const int f0 = fq0 + ft * 16 + kg * 4;
    const f32x4 g4 = *(const f32x4*)(g + f0);
    const f32x4 e4 = *(const f32x4*)(be + f0);
#pragma unroll
    for (int rt = 0; rt < 2; ++rt) {
      const int row = rt * 16 + lm;
      float h[4];
#pragma unroll
      for (int rg = 0; rg < 4; ++rg) {
        float y = (acc[ft][rt][rg] - mean[rt]) * rstd[rt] * g4[rg] + e4[rg];
        h[rg] = y * (1.0f / (1.0f + __expf(-y)));
      }
      uint2 w; w.x = pack2bf(h[0], h[1]); w.y = pack2bf(h[2], h[3]);
      int byte = row * (ND * 2) + f0 * 2;
      byte ^= ((row & 7) << 4);
      *(uint2*)(Hb + byte) = w;
    }
  }
}

__global__ __launch_bounds__(THREADS, 2) void fused_kernel(
    const float* __restrict__ obs, const float* __restrict__ actions,
    const float* __restrict__ rewards, const float* __restrict__ bootstrap,
    const float* __restrict__ discount, const float* __restrict__ q_support,
    const float* __restrict__ b1, const float* __restrict__ g1, const float* __restrict__ be1,
    const float* __restrict__ b2, const float* __restrict__ g2, const float* __restrict__ be2,
    const float* __restrict__ b3, const float* __restrict__ g3, const float* __restrict__ be3,
    const float* __restrict__ b4,
    const unsigned short* __restrict__ ws,
    float* __restrict__ out)
{
  __shared__ __align__(16) unsigned char smem[LDS_TOTAL];
  const int tid  = threadIdx.x;
  const int fq   = tid >> 6;          // wave = feature-quarter
  const int lane = tid & 63;
  const int lm   = lane & 15;
  const int kg   = lane >> 4;
  const int row0 = blockIdx.x * 32;

  const unsigned short* W1T = ws;
  const unsigned short* W2T = ws + 81920;
  const unsigned short* W3T = ws + 212992;
  const unsigned short* W4T = ws + 245760;

  float* zsL  = (float*)(smem + OFF_ZS);
  float* b4L  = (float*)(smem + OFF_B4);
  float* redL = (float*)(smem + OFF_RED);

  // per-row scalars straight to registers (each lane owns rows rt*16+lm)
  float rw[2], bt[2], dc[2];
#pragma unroll
  for (int rt = 0; rt < 2; ++rt) {
    const int r = row0 + rt * 16 + lm;
    rw[rt] = rewards[r]; bt[rt] = bootstrap[r]; dc[rt] = discount[r];
  }

  // stage q_support / b4 (padded to 256, avoids OOB vector loads)
  zsL[tid] = (tid < 251) ? q_support[tid] : 0.f;
  b4L[tid] = (tid < 251) ? b4[tid] : 0.f;

  // stage X = concat(obs, actions) bf16 [32][160], swizzled
  {
    unsigned char* Xb = smem + OFF_X;
#pragma unroll
    for (int it = 0; it < 5; ++it) {
      const int qq = it * THREADS + tid;     // 0..1279, 40 float4 per row
      const int r  = qq / 40;
      const int c4 = (qq - r * 40) * 4;
      float4 v;
      if (c4 < 128) v = *(const float4*)(obs + (size_t)(row0 + r) * 128 + c4);
      else          v = *(const float4*)(actions + (size_t)(row0 + r) * 32 + (c4 - 128));
      uint2 w; w.x = pack2bf(v.x, v.y); w.y = pack2bf(v.z, v.w);
      int byte = r * 320 + c4 * 2;
      byte ^= ((r & 7) << 4);
      *(uint2*)(Xb + byte) = w;
    }
  }
  __syncthreads();

  // ---- layer 1: [512 feats] x K=160 ----
  f32x4 acc1[8][2];
#pragma unroll
  for (int i = 0; i < 8; ++i) { acc1[i][0] = f32x4{0,0,0,0}; acc1[i][1] = f32x4{0,0,0,0}; }
  gemm_w<160, 8>(W1T, smem + OFF_X, fq * 128, acc1);
  ln_silu_store<512, 8>(acc1, b1, g1, be1, smem + OFF_H1, redL, fq);
  __syncthreads();

  // ---- layer 2: [256 feats] x K=512 ----
  f32x4 acc2[4][2];
#pragma unroll
  for (int i = 0; i < 4; ++i) { acc2[i][0] = f32x4{0,0,0,0}; acc2[i][1] = f32x4{0,0,0,0}; }
  gemm_w<512, 4>(W2T, smem + OFF_H1, fq * 64, acc2);
  ln_silu_store<256, 4>(acc2, b2, g2, be2, smem + OFF_H2, redL, fq);
  // H1 dead (ln's internal barrier passed) -> zero proj buffer aliasing it
  float* projL = (float*)(smem + OFF_H1);
  for (int i = tid; i < 32 * 251; i += THREADS) projL[i] = 0.f;
  __syncthreads();

  // ---- layer 3: [128 feats] x K=256 ----
  f32x4 acc3[2][2];
#pragma unroll
  for (int i = 0; i < 2; ++i) { acc3[i][0] = f32x4{0,0,0,0}; acc3[i][1] = f32x4{0,0,0,0}; }
  gemm_w<256, 2>(W3T, smem + OFF_H2, fq * 32, acc3);
  ln_silu_store<128, 2>(acc3, b3, g3, be3, smem + OFF_X, redL, fq);  // H3 aliases X
  __syncthreads();

  // ---- layer 4: logits [256pad feats] x K=128 ----
  f32x4 acc4[4][2];
#pragma unroll
  for (int i = 0; i < 4; ++i) { acc4[i][0] = f32x4{0,0,0,0}; acc4[i][1] = f32x4{0,0,0,0}; }
  gemm_w<128, 4>(W4T, smem + OFF_X, fq * 64, acc4);

  float lv[4][2][4];
#pragma unroll
  for (int ft = 0; ft < 4; ++ft) {
    const int f0 = fq * 64 + ft * 16 + kg * 4;
    const f32x4 bb = *(const f32x4*)(b4L + f0);
#pragma unroll
    for (int rt = 0; rt < 2; ++rt)
#pragma unroll
      for (int rg = 0; rg < 4; ++rg) {
        const int f = f0 + rg;
        lv[ft][rt][rg] = (f < 251) ? (acc4[ft][rt][rg] + bb[rg]) : -1e30f;
      }
  }

  // ---- softmax over 251 features per row ----
#pragma unroll
  for (int rt = 0; rt < 2; ++rt) {
    float m = lv[0][rt][0];
#pragma unroll
    for (int ft = 0; ft < 4; ++ft)
#pragma unroll
      for (int rg = 0; rg < 4; ++rg) m = fmaxf(m, lv[ft][rt][rg]);
    m = fmaxf(m, __shfl_xor(m, 16));
    m = fmaxf(m, __shfl_xor(m, 32));
    if (lane < 16) redL[(rt * 16 + lm) * 4 + fq] = m;
  }
  __syncthreads();
  float gm[2];
#pragma unroll
  for (int rt = 0; rt < 2; ++rt) {
    const int row = rt * 16 + lm;
    gm[rt] = fmaxf(fmaxf(redL[row * 4 + 0], redL[row * 4 + 1]),
                   fmaxf(redL[row * 4 + 2], redL[row * 4 + 3]));
  }
  __syncthreads();   // red reuse
#pragma unroll
  for (int rt = 0; rt < 2; ++rt) {
    float E = 0.f;
#pragma unroll
    for (int ft = 0; ft < 4; ++ft)
#pragma unroll
      for (int rg = 0; rg < 4; ++rg) {
        float e = __expf(lv[ft][rt][rg] - gm[rt]);
        lv[ft][rt][rg] = e;
        E += e;
      }
    E += __shfl_xor(E, 16); E += __shfl_xor(E, 32);
    if (lane < 16) redL[(rt * 16 + lm) * 4 + fq] = E;
  }
  __syncthreads();
  float inv[2];
#pragma unroll
  for (int rt = 0; rt < 2; ++rt) {
    const int row = rt * 16 + lm;
    inv[rt] = 1.0f / (redL[row * 4 + 0] + redL[row * 4 + 1] +
                      redL[row * 4 + 2] + redL[row * 4 + 3]);
  }

  // ---- C51 projection scatter (bit-exact bin math vs numpy) ----
  constexpr float DZF = 20.0f / 250.0f;
#pragma unroll
  for (int ft = 0; ft < 4; ++ft) {
    const int f0 = fq * 64 + ft * 16 + kg * 4;
    const f32x4 z4 = *(const f32x4*)(zsL + f0);
#pragma unroll
    for (int rt = 0; rt < 2; ++rt) {
      const int base = (rt * 16 + lm) * 251;
      const float bd = __fmul_rn(bt[rt], dc[rt]);
#pragma unroll
      for (int rg = 0; rg < 4; ++rg) {
        const int f = f0 + rg;
        if (f < 251) {
          const float p = lv[ft][rt][rg] * inv[rt];
          float t = __fadd_rn(rw[rt], __fmul_rn(bd, z4[rg]));
          t = fminf(fmaxf(t, -10.0f), 10.0f);
          const float bfr = __fdiv_rn(__fsub_rn(t, -10.0f), DZF);
          const float fl = floorf(bfr), fu = ceilf(bfr);
          int l = (int)fl, u = (int)fu;
          if (fl == fu) { if (l > 0) --l; else ++u; }
          atomicAdd(projL + base + l, p * ((float)u - bfr));
          atomicAdd(projL + base + u, p * (bfr - (float)l));
        }
      }
    }
  }
  __syncthreads();

  // ---- write out: block slice is contiguous (32*251 floats = 2008 float4) ----
  const float4* ps = (const float4*)projL;
  float4* po = (float4*)(out + (size_t)row0 * 251);
  for (int i = tid; i < 2008; i += THREADS) po[i] = ps[i];
}

extern "C" void kernel_launch(void* const* d_in, const int* in_sizes, int n_in,
                              void* d_out, int out_size, void* d_ws, size_t ws_size,
                              hipStream_t stream) {
  const float* obs  = (const float*)d_in[0];
  const float* act  = (const float*)d_in[1];
  const float* rew  = (const float*)d_in[2];
  const float* boot = (const float*)d_in[3];
  const float* disc = (const float*)d_in[4];
  const float* zs   = (const float*)d_in[5];
  const float* W1   = (const float*)d_in[6];
  const float* b1   = (const float*)d_in[7];
  const float* g1   = (const float*)d_in[8];
  const float* be1  = (const float*)d_in[9];
  const float* W2   = (const float*)d_in[10];
  const float* b2   = (const float*)d_in[11];
  const float* g2   = (const float*)d_in[12];
  const float* be2  = (const float*)d_in[13];
  const float* W3   = (const float*)d_in[14];
  const float* b3   = (const float*)d_in[15];
  const float* g3   = (const float*)d_in[16];
  const float* be3  = (const float*)d_in[17];
  const float* W4   = (const float*)d_in[18];
  const float* b4   = (const float*)d_in[19];
  unsigned short* wsp = (unsigned short*)d_ws;

  const int Bn = in_sizes[2];          // batch = 131072
  prep_kernel<<<(278528 + THREADS - 1) / THREADS, THREADS, 0, stream>>>(W1, W2, W3, W4, wsp);
  fused_kernel<<<Bn / 32, THREADS, 0, stream>>>(obs, act, rew, boot, disc, zs,
      b1, g1, be1, b2, g2, be2, b3, g3, be3, b4, wsp, (float*)d_out);
}